// Round 11
// baseline (2006.618 us; speedup 1.0000x reference)
//
#include <hip/hip_runtime.h>

// Problem constants: N=32768 pts, C=256 clusters, P=128, E=1024 edges,
// grid 32^3. Channels 1->16->32->64, three stride-2 SAME convs.
#define PPC 128

// Fractional box-overlap of [v, v+gs] with cell [i/32, (i+1)/32], divided by gs.
__device__ __forceinline__ float ovlap(float v, float gs, float inv_gs, int i) {
  const float ns = 0.03125f;                 // 1/32, exact
  float lo = (float)i * ns;                  // exact (multiple of 2^-5)
  float o  = fminf(v + gs, lo + ns) - fmaxf(v, lo);
  return fmaxf(o, 0.0f) * inv_gs;
}

// ---------------------------------------------------------------------------
// Kernel 1: per-cluster voxelize (in LDS) + conv1 (preact, no bias/relu)
//   y1[c][oc(16)][z16][y16][x16]  (fp32, 64 MB in d_ws)   (unchanged)
// ---------------------------------------------------------------------------
__global__ __launch_bounds__(256) void k_vox_conv1(
    const float* __restrict__ data,           // [32768,5]
    const int*   __restrict__ clusts,         // [C,128]
    const unsigned char* __restrict__ maskb,  // [C,128] bool bytes (or int32 - detected)
    const float* __restrict__ W1,             // [16,27]
    float* __restrict__ y1)                   // [C,16,4096]
{
  __shared__ float vox[32768];
  __shared__ float rmn[PPC * 3];
  __shared__ float rmx[PPC * 3];
  const int c = blockIdx.x;
  const int t = threadIdx.x;

  for (int i = t; i < 32768; i += 256) vox[i] = 0.f;

  const bool m32 = (maskb[1] == 0);   // mask dtype sniff (all-true mask)

  if (t < PPC) {
    int idx = clusts[c * PPC + t];
    const float* dp = data + idx * 5;
    bool m = m32 ? (((const int*)maskb)[c * PPC + t] != 0)
                 : (maskb[c * PPC + t] != 0);
#pragma unroll
    for (int d = 0; d < 3; ++d) {
      float p = dp[d];
      rmn[t * 3 + d] = m ? p : 1e9f;
      rmx[t * 3 + d] = m ? p : -1e9f;
    }
  }
  __syncthreads();
  for (int off = 64; off >= 1; off >>= 1) {
    if (t < off) {
#pragma unroll
      for (int d = 0; d < 3; ++d) {
        rmn[t * 3 + d] = fminf(rmn[t * 3 + d], rmn[(t + off) * 3 + d]);
        rmx[t * 3 + d] = fmaxf(rmx[t * 3 + d], rmx[(t + off) * 3 + d]);
      }
    }
    __syncthreads();
  }
  const float mn0 = rmn[0], mn1 = rmn[1], mn2 = rmn[2];
  const float rg0 = rmx[0] - mn0, rg1 = rmx[1] - mn1, rg2 = rmx[2] - mn2;
  const float mr = fmaxf(rg0, fmaxf(rg1, rg2)) + 1.0f;
  const float gs = 1.0f / mr;
  const float inv_gs = 1.0f / gs;

  {  // scatter: 2 threads per point, split outer-i by parity
    const int p = t >> 1, h = t & 1;
    int idx = clusts[c * PPC + p];
    const float* dp = data + idx * 5;
    bool m = m32 ? (((const int*)maskb)[c * PPC + p] != 0)
                 : (maskb[c * PPC + p] != 0);
    float w = m ? dp[4] : 0.f;
    if (w != 0.f) {
      float v0 = (dp[0] - mn0 - rg0 * 0.5f - 0.5f) * gs + 0.5f;
      float v1 = (dp[1] - mn1 - rg1 * 0.5f - 0.5f) * gs + 0.5f;
      float v2 = (dp[2] - mn2 - rg2 * 0.5f - 0.5f) * gs + 0.5f;
      int i0 = max(0, (int)floorf(v0 * 32.f) - 1), i1 = min(31, (int)floorf((v0 + gs) * 32.f) + 1);
      int j0 = max(0, (int)floorf(v1 * 32.f) - 1), j1 = min(31, (int)floorf((v1 + gs) * 32.f) + 1);
      int k0 = max(0, (int)floorf(v2 * 32.f) - 1), k1 = min(31, (int)floorf((v2 + gs) * 32.f) + 1);
      for (int i = i0 + h; i <= i1; i += 2) {
        float oi = ovlap(v0, gs, inv_gs, i);
        if (oi <= 0.f) continue;
        float wi = w * oi;
        for (int j = j0; j <= j1; ++j) {
          float oj = ovlap(v1, gs, inv_gs, j);
          if (oj <= 0.f) continue;
          float wij = wi * oj;
          for (int k = k0; k <= k1; ++k) {
            float ok = ovlap(v2, gs, inv_gs, k);
            if (ok > 0.f) atomicAdd(&vox[(i << 10) + (j << 5) + k], wij * ok);
          }
        }
      }
    }
  }
  __syncthreads();

  // conv1: 16 spatials/thread, 16 oc each. SAME: in = 2o+t, right-pad at 32.
  for (int si = 0; si < 16; ++si) {
    int s = t + (si << 8);
    int oz = s >> 8, oy = (s >> 4) & 15, ox = s & 15;
    float xv[27];
#pragma unroll
    for (int td = 0; td < 3; ++td)
#pragma unroll
      for (int th = 0; th < 3; ++th)
#pragma unroll
        for (int tw = 0; tw < 3; ++tw) {
          int z = 2 * oz + td, y = 2 * oy + th, x = 2 * ox + tw;
          bool okb = (z < 32) & (y < 32) & (x < 32);
          xv[(td * 3 + th) * 3 + tw] = okb ? vox[(z << 10) + (y << 5) + x] : 0.f;
        }
#pragma unroll
    for (int oc = 0; oc < 16; ++oc) {
      float a = 0.f;
#pragma unroll
      for (int tp = 0; tp < 27; ++tp) a = fmaf(W1[oc * 27 + tp], xv[tp], a);
      y1[(((c << 4) + oc) << 12) + s] = a;
    }
  }
}

// ---------------------------------------------------------------------------
// Kernel 2 (R10): T14 split kept; tap-major REBLOCKED to 8-oc granularity.
//  R9 failure: 32-deep oc inner loop (96 weight loads/group) + unroll-2 ic
//  body -> VGPR 164, occupancy 12%, 1880us. R10 bounds pressure:
//   - inner loop = 8 ocs (24 weight s_loads/group, fits SGPR file);
//     conv2 taps re-read 4x (216 ds_read/round vs R8's ~1700 re-streamed),
//     conv3 taps re-read 2x.
//   - #pragma unroll 1 on the ic loop (tight body, tight regalloc).
//   - staged regs capped at 16 (two half-staging, as R9 -- HW-verified maps).
//  Target: VGPR <= 128 (4 waves/SIMD band). If counter shows >128, this
//  round's read is "band halved" and we tune bounds next.
// ---------------------------------------------------------------------------
#define S1 4913                // 17*17*17 one-channel staging volume
__global__ __launch_bounds__(256) void k_edge(
    const void*  __restrict__ eidx_raw,       // [2,E] int32 or int64 (detected)
    const float* __restrict__ y1,             // [C,16,4096]
    const float* __restrict__ b1,             // 16
    const float* __restrict__ W2,             // [32,16,27]
    const float* __restrict__ b2,             // 32
    const float* __restrict__ W3,             // [64,32,27]
    const float* __restrict__ b3,             // 64
    const float* __restrict__ Wfc,            // [64,64] (k-major)
    const float* __restrict__ bfc,            // 64
    float* __restrict__ out,                  // [E,64]
    int E)
{
  __shared__ float smem[2 * S1 + 64];         // stage bufs / conv3 buf (aliased) + pooled
  float* pooled = smem + 2 * S1;
  const int e = blockIdx.x;
  const int t = threadIdx.x;

  // edge_index dtype sniff (values < 256 -> int64 high words are 0)
  const int* e32 = (const int*)eidx_raw;
  const long long* e64 = (const long long*)eidx_raw;
  const bool is64 = (e32[1] == 0) & (e32[3] == 0) & (e32[5] == 0) & (e32[7] == 0);
  const int ca = is64 ? (int)e64[e] : e32[e];
  const int cb = is64 ? (int)e64[E + e] : e32[E + e];
  const float* Ap = y1 + (size_t)ca * 65536;
  const float* Bp = y1 + (size_t)cb * 65536;

  float acc2[2][32];
#pragma unroll
  for (int h = 0; h < 2; ++h)
#pragma unroll
    for (int o = 0; o < 32; ++o) acc2[h][o] = 0.f;

  const int oz0 = t >> 6, oy0 = (t >> 3) & 7, ox0 = t & 7;  // conv2 spatial: s0, s1=s0+4z
  // float4 staging mapping (HW-verified R9/R10 runs): zl=t>>6, lane63=t&63
  const int zl = t >> 6, lane63 = t & 63, xq = t & 3;
  const int stwb = ((t >> 2) & 15) * 17 + 2 * xq;   // x=4xq+j -> cols {+0,+9,+1,+10}

  // zero both stage buffers (establishes pad cells: col 8, y=16, z=16)
  for (int i = t; i < 2 * S1; i += 256) smem[i] = 0.f;
  __syncthreads();                       // zero vs stage WAW race fix

  // ---- prologue: stage ch 0 into buf 0 ----
  {
    const float4* A4 = (const float4*)Ap;
    const float4* B4 = (const float4*)Bp;
    const float bb = b1[0];
#pragma unroll
    for (int b = 0; b < 4; ++b) {
      const int z = (b << 2) + zl;
      float4 av = A4[(z << 6) + lane63];
      float4 bv = B4[(z << 6) + lane63];
      const int w = z * 289 + stwb;
      smem[w]      = fmaxf(av.x + bv.x + bb, 0.f);
      smem[w + 9]  = fmaxf(av.y + bv.y + bb, 0.f);
      smem[w + 1]  = fmaxf(av.z + bv.z + bb, 0.f);
      smem[w + 10] = fmaxf(av.w + bv.w + bb, 0.f);
    }
  }
  __syncthreads();

  // ================= conv2: 16 rounds, dbuf, T14 order, 8-oc blocks ========
#pragma unroll 1
  for (int ic = 0; ic < 16; ++ic) {
    const int rb = (ic & 1) * S1 + oz0 * 578 + oy0 * 34;
    const float* wrow = W2 + ic * 27;
    const bool st = (ic < 15);
    const float4* An4 = (const float4*)(Ap + ((ic + 1) << 12));
    const float4* Bn4 = (const float4*)(Bp + ((ic + 1) << 12));
    const float bb = st ? b1[ic + 1] : 0.f;
    const int wb = ((ic + 1) & 1) * S1;

    float4 a0, a1, c0, c1;
    // issue half-0 loads (z 0..7 of next channel) BEFORE compute
    if (st) {
      a0 = An4[(zl << 6) + lane63];        c0 = Bn4[(zl << 6) + lane63];
      a1 = An4[((4 + zl) << 6) + lane63];  c1 = Bn4[((4 + zl) << 6) + lane63];
    }
    // oc-blocks 0,1 (oc 0..15): taps read per (ocb,g), 8-deep oc inner
#pragma unroll
    for (int ocb = 0; ocb < 2; ++ocb)
#pragma unroll
      for (int g = 0; g < 9; ++g) {
        const int b0 = rb + (g / 3) * 289 + (g % 3) * 17;
        const float t00 = smem[b0 + ox0], t01 = smem[b0 + 9 + ox0], t02 = smem[b0 + ox0 + 1];
        const float t10 = smem[b0 + 2312 + ox0], t11 = smem[b0 + 2312 + 9 + ox0], t12 = smem[b0 + 2312 + ox0 + 1];
        const int tp = g * 3;
#pragma unroll
        for (int o = 0; o < 8; ++o) {
          const int oc = (ocb << 3) + o;
          const float w0 = wrow[oc * 432 + tp];
          const float w1 = wrow[oc * 432 + tp + 1];
          const float w2 = wrow[oc * 432 + tp + 2];
          acc2[0][oc] = fmaf(w0, t00, acc2[0][oc]);
          acc2[0][oc] = fmaf(w1, t01, acc2[0][oc]);
          acc2[0][oc] = fmaf(w2, t02, acc2[0][oc]);
          acc2[1][oc] = fmaf(w0, t10, acc2[1][oc]);
          acc2[1][oc] = fmaf(w1, t11, acc2[1][oc]);
          acc2[1][oc] = fmaf(w2, t12, acc2[1][oc]);
        }
      }
    // write half-0 (vmcnt here), then issue half-1 loads
    if (st) {
      const int w0 = wb + zl * 289 + stwb;
      smem[w0]      = fmaxf(a0.x + c0.x + bb, 0.f);
      smem[w0 + 9]  = fmaxf(a0.y + c0.y + bb, 0.f);
      smem[w0 + 1]  = fmaxf(a0.z + c0.z + bb, 0.f);
      smem[w0 + 10] = fmaxf(a0.w + c0.w + bb, 0.f);
      const int w1 = wb + (4 + zl) * 289 + stwb;
      smem[w1]      = fmaxf(a1.x + c1.x + bb, 0.f);
      smem[w1 + 9]  = fmaxf(a1.y + c1.y + bb, 0.f);
      smem[w1 + 1]  = fmaxf(a1.z + c1.z + bb, 0.f);
      smem[w1 + 10] = fmaxf(a1.w + c1.w + bb, 0.f);
      a0 = An4[((8 + zl) << 6) + lane63];   c0 = Bn4[((8 + zl) << 6) + lane63];
      a1 = An4[((12 + zl) << 6) + lane63];  c1 = Bn4[((12 + zl) << 6) + lane63];
    }
    // oc-blocks 2,3 (oc 16..31)
#pragma unroll
    for (int ocb = 2; ocb < 4; ++ocb)
#pragma unroll
      for (int g = 0; g < 9; ++g) {
        const int b0 = rb + (g / 3) * 289 + (g % 3) * 17;
        const float t00 = smem[b0 + ox0], t01 = smem[b0 + 9 + ox0], t02 = smem[b0 + ox0 + 1];
        const float t10 = smem[b0 + 2312 + ox0], t11 = smem[b0 + 2312 + 9 + ox0], t12 = smem[b0 + 2312 + ox0 + 1];
        const int tp = g * 3;
#pragma unroll
        for (int o = 0; o < 8; ++o) {
          const int oc = (ocb << 3) + o;
          const float w0 = wrow[oc * 432 + tp];
          const float w1 = wrow[oc * 432 + tp + 1];
          const float w2 = wrow[oc * 432 + tp + 2];
          acc2[0][oc] = fmaf(w0, t00, acc2[0][oc]);
          acc2[0][oc] = fmaf(w1, t01, acc2[0][oc]);
          acc2[0][oc] = fmaf(w2, t02, acc2[0][oc]);
          acc2[1][oc] = fmaf(w0, t10, acc2[1][oc]);
          acc2[1][oc] = fmaf(w1, t11, acc2[1][oc]);
          acc2[1][oc] = fmaf(w2, t12, acc2[1][oc]);
        }
      }
    // write half-1
    if (st) {
      const int w0 = wb + (8 + zl) * 289 + stwb;
      smem[w0]      = fmaxf(a0.x + c0.x + bb, 0.f);
      smem[w0 + 9]  = fmaxf(a0.y + c0.y + bb, 0.f);
      smem[w0 + 1]  = fmaxf(a0.z + c0.z + bb, 0.f);
      smem[w0 + 10] = fmaxf(a0.w + c0.w + bb, 0.f);
      const int w1 = wb + (12 + zl) * 289 + stwb;
      smem[w1]      = fmaxf(a1.x + c1.x + bb, 0.f);
      smem[w1 + 9]  = fmaxf(a1.y + c1.y + bb, 0.f);
      smem[w1 + 1]  = fmaxf(a1.z + c1.z + bb, 0.f);
      smem[w1 + 10] = fmaxf(a1.w + c1.w + bb, 0.f);
    }
    __syncthreads();
  }

  // ================= conv3: 4 oc-quarters, padded [8][9][9][9] =============
  // zero ONCE (pads: z=8 plane, y=8 rows, col 4); interiors rewritten each q.
  for (int i = t; i < 5832; i += 256) smem[i] = 0.f;
  __syncthreads();

  float acc3[16];
#pragma unroll
  for (int o = 0; o < 16; ++o) acc3[o] = 0.f;
  const int l = t & 63, wid = t >> 6;
  const int OZ = l >> 4, OY = (l >> 2) & 3, OX = l & 3;     // conv3 spatial 4^3
  const int rb3 = OZ * 162 + OY * 18;                       // zz=2OZ, yy=2OY
  const int cox = (ox0 >> 1) + (ox0 & 1) * 5;               // x2-write column

#pragma unroll
  for (int q = 0; q < 4; ++q) {
#pragma unroll
    for (int h = 0; h < 2; ++h)
#pragma unroll
      for (int o = 0; o < 8; ++o) {
        const int oc = (q << 3) + o;           // compile-time (q,o unrolled)
        smem[o * 729 + (oz0 + (h << 2)) * 81 + oy0 * 9 + cox] =
            fmaxf(acc2[h][oc] + b2[oc], 0.f);
      }
    __syncthreads();
#pragma unroll 1
    for (int icl = 0; icl < 8; ++icl) {
      const int ic3 = (q << 3) + icl;
      const int bbse = icl * 729 + rb3;
      const float* wr3 = W3 + ic3 * 27;        // + oc*864
#pragma unroll
      for (int ob = 0; ob < 2; ++ob)           // 8-oc blocks: taps read 2x
#pragma unroll
        for (int g = 0; g < 9; ++g) {
          const int ba = bbse + (g / 3) * 81 + (g % 3) * 9;
          const float u0 = smem[ba + OX];      // x=2OX
          const float u1 = smem[ba + 5 + OX];  // x=2OX+1
          const float u2 = smem[ba + OX + 1];  // x=2OX+2 (OX=3 -> col4 pad = 0)
          const int tp = g * 3;
#pragma unroll
          for (int o = 0; o < 8; ++o) {
            const int oo = (ob << 3) + o;      // compile-time acc3 index
            const float* wr = wr3 + ((wid << 4) + oo) * 864;   // wave-uniform -> s_load
            acc3[oo] = fmaf(wr[tp],     u0, acc3[oo]);
            acc3[oo] = fmaf(wr[tp + 1], u1, acc3[oo]);
            acc3[oo] = fmaf(wr[tp + 2], u2, acc3[oo]);
          }
        }
    }
    __syncthreads();
  }

  // ================= bias+relu, mean-pool over 64 spatials, FC =============
#pragma unroll
  for (int o = 0; o < 16; ++o) {
    float r = fmaxf(acc3[o] + b3[(wid << 4) + o], 0.f);
    r += __shfl_xor(r, 1);
    r += __shfl_xor(r, 2);
    r += __shfl_xor(r, 4);
    r += __shfl_xor(r, 8);
    r += __shfl_xor(r, 16);
    r += __shfl_xor(r, 32);
    if (l == 0) pooled[(wid << 4) + o] = r * 0.015625f;  // /64
  }
  __syncthreads();
  if (t < 64) {
    float a = bfc[t];
#pragma unroll 8
    for (int k = 0; k < 64; ++k) a = fmaf(pooled[k], Wfc[(k << 6) + t], a);
    out[e * 64 + t] = a;
  }
}

// ---------------------------------------------------------------------------
extern "C" void kernel_launch(void* const* d_in, const int* in_sizes, int n_in,
                              void* d_out, int out_size, void* d_ws, size_t ws_size,
                              hipStream_t stream) {
  const float* data = (const float*)d_in[0];
  const int*   clusts = (const int*)d_in[1];
  const unsigned char* maskb = (const unsigned char*)d_in[2];
  const void*  eidx = d_in[3];
  const float* W1 = (const float*)d_in[4];
  const float* b1 = (const float*)d_in[5];
  const float* W2 = (const float*)d_in[6];
  const float* b2 = (const float*)d_in[7];
  const float* W3 = (const float*)d_in[8];
  const float* b3 = (const float*)d_in[9];
  const float* Wfc = (const float*)d_in[10];
  const float* bfc = (const float*)d_in[11];

  const int C = in_sizes[1] / PPC;   // 256
  const int E = in_sizes[3] / 2;     // 1024

  float* y1 = (float*)d_ws;          // C*16*4096 floats = 64 MB

  k_vox_conv1<<<C, 256, 0, stream>>>(data, clusts, maskb, W1, y1);
  k_edge<<<E, 256, 0, stream>>>(eidx, y1, b1, W2, b2, W3, b3, Wfc, bfc,
                                (float*)d_out, E);
}

// Round 12
// 1804.353 us; speedup vs baseline: 1.1121x; 1.1121x over previous
//
#include <hip/hip_runtime.h>

// Problem constants: N=32768 pts, C=256 clusters, P=128, E=1024 edges,
// grid 32^3. Channels 1->16->32->64, three stride-2 SAME convs.
#define PPC 128

// Fractional box-overlap of [v, v+gs] with cell [i/32, (i+1)/32], divided by gs.
__device__ __forceinline__ float ovlap(float v, float gs, float inv_gs, int i) {
  const float ns = 0.03125f;                 // 1/32, exact
  float lo = (float)i * ns;                  // exact (multiple of 2^-5)
  float o  = fminf(v + gs, lo + ns) - fmaxf(v, lo);
  return fmaxf(o, 0.0f) * inv_gs;
}

// ---------------------------------------------------------------------------
// Kernel 1: per-cluster voxelize (in LDS) + conv1 (preact, no bias/relu)
//   y1[c][oc(16)][z16][y16][x16]  (fp32, 64 MB in d_ws)   (unchanged)
// ---------------------------------------------------------------------------
__global__ __launch_bounds__(256) void k_vox_conv1(
    const float* __restrict__ data,           // [32768,5]
    const int*   __restrict__ clusts,         // [C,128]
    const unsigned char* __restrict__ maskb,  // [C,128] bool bytes (or int32 - detected)
    const float* __restrict__ W1,             // [16,27]
    float* __restrict__ y1)                   // [C,16,4096]
{
  __shared__ float vox[32768];
  __shared__ float rmn[PPC * 3];
  __shared__ float rmx[PPC * 3];
  const int c = blockIdx.x;
  const int t = threadIdx.x;

  for (int i = t; i < 32768; i += 256) vox[i] = 0.f;

  const bool m32 = (maskb[1] == 0);   // mask dtype sniff (all-true mask)

  if (t < PPC) {
    int idx = clusts[c * PPC + t];
    const float* dp = data + idx * 5;
    bool m = m32 ? (((const int*)maskb)[c * PPC + t] != 0)
                 : (maskb[c * PPC + t] != 0);
#pragma unroll
    for (int d = 0; d < 3; ++d) {
      float p = dp[d];
      rmn[t * 3 + d] = m ? p : 1e9f;
      rmx[t * 3 + d] = m ? p : -1e9f;
    }
  }
  __syncthreads();
  for (int off = 64; off >= 1; off >>= 1) {
    if (t < off) {
#pragma unroll
      for (int d = 0; d < 3; ++d) {
        rmn[t * 3 + d] = fminf(rmn[t * 3 + d], rmn[(t + off) * 3 + d]);
        rmx[t * 3 + d] = fmaxf(rmx[t * 3 + d], rmx[(t + off) * 3 + d]);
      }
    }
    __syncthreads();
  }
  const float mn0 = rmn[0], mn1 = rmn[1], mn2 = rmn[2];
  const float rg0 = rmx[0] - mn0, rg1 = rmx[1] - mn1, rg2 = rmx[2] - mn2;
  const float mr = fmaxf(rg0, fmaxf(rg1, rg2)) + 1.0f;
  const float gs = 1.0f / mr;
  const float inv_gs = 1.0f / gs;

  {  // scatter: 2 threads per point, split outer-i by parity
    const int p = t >> 1, h = t & 1;
    int idx = clusts[c * PPC + p];
    const float* dp = data + idx * 5;
    bool m = m32 ? (((const int*)maskb)[c * PPC + p] != 0)
                 : (maskb[c * PPC + p] != 0);
    float w = m ? dp[4] : 0.f;
    if (w != 0.f) {
      float v0 = (dp[0] - mn0 - rg0 * 0.5f - 0.5f) * gs + 0.5f;
      float v1 = (dp[1] - mn1 - rg1 * 0.5f - 0.5f) * gs + 0.5f;
      float v2 = (dp[2] - mn2 - rg2 * 0.5f - 0.5f) * gs + 0.5f;
      int i0 = max(0, (int)floorf(v0 * 32.f) - 1), i1 = min(31, (int)floorf((v0 + gs) * 32.f) + 1);
      int j0 = max(0, (int)floorf(v1 * 32.f) - 1), j1 = min(31, (int)floorf((v1 + gs) * 32.f) + 1);
      int k0 = max(0, (int)floorf(v2 * 32.f) - 1), k1 = min(31, (int)floorf((v2 + gs) * 32.f) + 1);
      for (int i = i0 + h; i <= i1; i += 2) {
        float oi = ovlap(v0, gs, inv_gs, i);
        if (oi <= 0.f) continue;
        float wi = w * oi;
        for (int j = j0; j <= j1; ++j) {
          float oj = ovlap(v1, gs, inv_gs, j);
          if (oj <= 0.f) continue;
          float wij = wi * oj;
          for (int k = k0; k <= k1; ++k) {
            float ok = ovlap(v2, gs, inv_gs, k);
            if (ok > 0.f) atomicAdd(&vox[(i << 10) + (j << 5) + k], wij * ok);
          }
        }
      }
    }
  }
  __syncthreads();

  // conv1: 16 spatials/thread, 16 oc each. SAME: in = 2o+t, right-pad at 32.
  for (int si = 0; si < 16; ++si) {
    int s = t + (si << 8);
    int oz = s >> 8, oy = (s >> 4) & 15, ox = s & 15;
    float xv[27];
#pragma unroll
    for (int td = 0; td < 3; ++td)
#pragma unroll
      for (int th = 0; th < 3; ++th)
#pragma unroll
        for (int tw = 0; tw < 3; ++tw) {
          int z = 2 * oz + td, y = 2 * oy + th, x = 2 * ox + tw;
          bool okb = (z < 32) & (y < 32) & (x < 32);
          xv[(td * 3 + th) * 3 + tw] = okb ? vox[(z << 10) + (y << 5) + x] : 0.f;
        }
#pragma unroll
    for (int oc = 0; oc < 16; ++oc) {
      float a = 0.f;
#pragma unroll
      for (int tp = 0; tp < 27; ++tp) a = fmaf(W1[oc * 27 + tp], xv[tp], a);
      y1[(((c << 4) + oc) << 12) + s] = a;
    }
  }
}

// ---------------------------------------------------------------------------
// Kernel 2 (R12): 512-thread blocks -- occupancy/latency-hiding A/B vs R8.
//  R9/R11 tap-major REVERTED (conflicts scale with read count -> R8 wasn't
//  re-streaming; conflict cost ~50us of 810 -> not the limiter). R8's
//  residual 62% idle attributed to 4-waves/SIMD barrier convoys. R12: same
//  algorithm/layout/total-FLOPs, 1 spatial/thread (acc2[32]), td-blocked
//  taps (9 live) + oc-pair streams -> VGPR target <=64 -> 8 waves/SIMD,
//  32 waves/CU at 4 blocks/CU (LDS 39.6KB unchanged). Weight s_loads stay
//  contiguous 27-float rows (SMEM-friendly; R11's strided pattern reverted).
//  T14 split kept: loads issued before FMAs, LDS writes after.
// ---------------------------------------------------------------------------
#define S1 4913                // 17*17*17 one-channel staging volume
__global__ __launch_bounds__(512) void k_edge(
    const void*  __restrict__ eidx_raw,       // [2,E] int32 or int64 (detected)
    const float* __restrict__ y1,             // [C,16,4096]
    const float* __restrict__ b1,             // 16
    const float* __restrict__ W2,             // [32,16,27]
    const float* __restrict__ b2,             // 32
    const float* __restrict__ W3,             // [64,32,27]
    const float* __restrict__ b3,             // 64
    const float* __restrict__ Wfc,            // [64,64] (k-major)
    const float* __restrict__ bfc,            // 64
    float* __restrict__ out,                  // [E,64]
    int E)
{
  __shared__ float smem[2 * S1 + 64];         // stage bufs / conv3 buf (aliased) + pooled
  float* pooled = smem + 2 * S1;
  const int e = blockIdx.x;
  const int t = threadIdx.x;                  // 0..511

  // edge_index dtype sniff (values < 256 -> int64 high words are 0)
  const int* e32 = (const int*)eidx_raw;
  const long long* e64 = (const long long*)eidx_raw;
  const bool is64 = (e32[1] == 0) & (e32[3] == 0) & (e32[5] == 0) & (e32[7] == 0);
  const int ca = is64 ? (int)e64[e] : e32[e];
  const int cb = is64 ? (int)e64[E + e] : e32[E + e];
  const float* Ap = y1 + (size_t)ca * 65536;
  const float* Bp = y1 + (size_t)cb * 65536;

  float acc2[32];
#pragma unroll
  for (int o = 0; o < 32; ++o) acc2[o] = 0.f;

  // conv2 spatial: ONE output per thread
  const int oz0 = t >> 6, oy0 = (t >> 3) & 7, ox0 = t & 7;
  // float4 staging map: v = pass*2048 + 4t -> z=v>>8, y=(v>>4)&15, x=v&15
  // parity cols: x=4q+{0,1,2,3} -> stw + {0,9,1,10}, stw = y*17 + 2q
  const int stw = ((t >> 2) & 15) * 17 + 2 * (t & 3);
  const int sz0 = t >> 6;                     // pass0 z (0..7); pass1 z = 8+sz0

  // zero both stage buffers (establishes pad cells: col 8, y=16, z=16)
  for (int i = t; i < 2 * S1; i += 512) smem[i] = 0.f;
  __syncthreads();                            // zero vs stage WAW race fix

  // ---- prologue: stage ch 0 into buf 0 ----
  {
    const float4* A4 = (const float4*)Ap;
    const float4* B4 = (const float4*)Bp;
    const float bb = b1[0];
    float4 av0 = A4[t],      bv0 = B4[t];
    float4 av1 = A4[512 + t], bv1 = B4[512 + t];
    const int w0 = sz0 * 289 + stw;
    smem[w0]      = fmaxf(av0.x + bv0.x + bb, 0.f);
    smem[w0 + 9]  = fmaxf(av0.y + bv0.y + bb, 0.f);
    smem[w0 + 1]  = fmaxf(av0.z + bv0.z + bb, 0.f);
    smem[w0 + 10] = fmaxf(av0.w + bv0.w + bb, 0.f);
    const int w1 = (8 + sz0) * 289 + stw;
    smem[w1]      = fmaxf(av1.x + bv1.x + bb, 0.f);
    smem[w1 + 9]  = fmaxf(av1.y + bv1.y + bb, 0.f);
    smem[w1 + 1]  = fmaxf(av1.z + bv1.z + bb, 0.f);
    smem[w1 + 10] = fmaxf(av1.w + bv1.w + bb, 0.f);
  }
  __syncthreads();

  // ================= conv2: 16 rounds, dbuf, T14 order =================
#pragma unroll 1
  for (int ic = 0; ic < 16; ++ic) {
    const int rb = (ic & 1) * S1 + oz0 * 578 + oy0 * 34;
    const float* wrow = W2 + ic * 27;
    const bool st = (ic < 15);
    float4 a0, a1, c0, c1;
    if (st) {                                 // issue next-channel loads early
      const float4* An4 = (const float4*)(Ap + ((ic + 1) << 12));
      const float4* Bn4 = (const float4*)(Bp + ((ic + 1) << 12));
      a0 = An4[t];        c0 = Bn4[t];
      a1 = An4[512 + t];  c1 = Bn4[512 + t];
    }
    // td-blocked taps (9 live regs), oc-pair FMA streams
#pragma unroll
    for (int td = 0; td < 3; ++td) {
      float xv[9];
#pragma unroll
      for (int th = 0; th < 3; ++th) {
        const int b0 = rb + td * 289 + th * 17;
        xv[th * 3 + 0] = smem[b0 + ox0];      // x = 2ox0
        xv[th * 3 + 1] = smem[b0 + 9 + ox0];  // x = 2ox0+1
        xv[th * 3 + 2] = smem[b0 + ox0 + 1];  // x = 2ox0+2 (ox0=7 -> col8 pad)
      }
#pragma unroll
      for (int ocp = 0; ocp < 16; ++ocp) {
        const float* wa = wrow + (2 * ocp) * 432 + td * 9;       // s_load, contig 9
        const float* wc = wrow + (2 * ocp + 1) * 432 + td * 9;
#pragma unroll
        for (int j = 0; j < 9; ++j) {
          acc2[2 * ocp]     = fmaf(wa[j], xv[j], acc2[2 * ocp]);
          acc2[2 * ocp + 1] = fmaf(wc[j], xv[j], acc2[2 * ocp + 1]);
        }
      }
    }
    if (st) {                                 // write staged channel (other buf)
      const float bb = b1[ic + 1];
      const int wbuf = ((ic + 1) & 1) * S1;
      const int w0 = wbuf + sz0 * 289 + stw;
      smem[w0]      = fmaxf(a0.x + c0.x + bb, 0.f);
      smem[w0 + 9]  = fmaxf(a0.y + c0.y + bb, 0.f);
      smem[w0 + 1]  = fmaxf(a0.z + c0.z + bb, 0.f);
      smem[w0 + 10] = fmaxf(a0.w + c0.w + bb, 0.f);
      const int w1 = wbuf + (8 + sz0) * 289 + stw;
      smem[w1]      = fmaxf(a1.x + c1.x + bb, 0.f);
      smem[w1 + 9]  = fmaxf(a1.y + c1.y + bb, 0.f);
      smem[w1 + 1]  = fmaxf(a1.z + c1.z + bb, 0.f);
      smem[w1 + 10] = fmaxf(a1.w + c1.w + bb, 0.f);
    }
    __syncthreads();
  }

  // ================= conv3: 4 oc-quarters, padded [8][9][9][9] =============
  // zero ONCE (pads: z=8 plane, y=8 rows, col 4); interiors rewritten each q.
  for (int i = t; i < 5832; i += 512) smem[i] = 0.f;
  __syncthreads();

  float acc3[8];
#pragma unroll
  for (int o = 0; o < 8; ++o) acc3[o] = 0.f;
  const int l = t & 63, wid = t >> 6;         // wid 0..7: 8 oc each
  const int OZ = l >> 4, OY = (l >> 2) & 3, OX = l & 3;   // conv3 spatial 4^3
  const int rb3 = OZ * 162 + OY * 18;
  const int cox = (ox0 >> 1) + (ox0 & 1) * 5;             // x2-write column

#pragma unroll
  for (int q = 0; q < 4; ++q) {
#pragma unroll
    for (int o = 0; o < 8; ++o) {
      const int oc = (q << 3) + o;            // compile-time (q,o unrolled)
      smem[o * 729 + oz0 * 81 + oy0 * 9 + cox] = fmaxf(acc2[oc] + b2[oc], 0.f);
    }
    __syncthreads();
#pragma unroll 1
    for (int icl = 0; icl < 8; ++icl) {
      const int ic3 = (q << 3) + icl;
      const int bbse = icl * 729 + rb3;
#pragma unroll
      for (int g = 0; g < 9; ++g) {
        const int ba = bbse + (g / 3) * 81 + (g % 3) * 9;
        const float u0 = smem[ba + OX];       // x=2OX
        const float u1 = smem[ba + 5 + OX];   // x=2OX+1
        const float u2 = smem[ba + OX + 1];   // x=2OX+2 (OX=3 -> col4 pad = 0)
        const int tp = g * 3;
#pragma unroll
        for (int o = 0; o < 8; ++o) {
          const float* wr = W3 + (((wid << 3) + o) * 32 + ic3) * 27;  // wave-uniform
          acc3[o] = fmaf(wr[tp],     u0, acc3[o]);
          acc3[o] = fmaf(wr[tp + 1], u1, acc3[o]);
          acc3[o] = fmaf(wr[tp + 2], u2, acc3[o]);
        }
      }
    }
    __syncthreads();
  }

  // ================= bias+relu, mean-pool over 64 spatials, FC =============
#pragma unroll
  for (int o = 0; o < 8; ++o) {
    float r = fmaxf(acc3[o] + b3[(wid << 3) + o], 0.f);
    r += __shfl_xor(r, 1);
    r += __shfl_xor(r, 2);
    r += __shfl_xor(r, 4);
    r += __shfl_xor(r, 8);
    r += __shfl_xor(r, 16);
    r += __shfl_xor(r, 32);
    if (l == 0) pooled[(wid << 3) + o] = r * 0.015625f;  // /64
  }
  __syncthreads();
  if (t < 64) {
    float a = bfc[t];
#pragma unroll 8
    for (int k = 0; k < 64; ++k) a = fmaf(pooled[k], Wfc[(k << 6) + t], a);
    out[e * 64 + t] = a;
  }
}

// ---------------------------------------------------------------------------
extern "C" void kernel_launch(void* const* d_in, const int* in_sizes, int n_in,
                              void* d_out, int out_size, void* d_ws, size_t ws_size,
                              hipStream_t stream) {
  const float* data = (const float*)d_in[0];
  const int*   clusts = (const int*)d_in[1];
  const unsigned char* maskb = (const unsigned char*)d_in[2];
  const void*  eidx = d_in[3];
  const float* W1 = (const float*)d_in[4];
  const float* b1 = (const float*)d_in[5];
  const float* W2 = (const float*)d_in[6];
  const float* b2 = (const float*)d_in[7];
  const float* W3 = (const float*)d_in[8];
  const float* b3 = (const float*)d_in[9];
  const float* Wfc = (const float*)d_in[10];
  const float* bfc = (const float*)d_in[11];

  const int C = in_sizes[1] / PPC;   // 256
  const int E = in_sizes[3] / 2;     // 1024

  float* y1 = (float*)d_ws;          // C*16*4096 floats = 64 MB

  k_vox_conv1<<<C, 256, 0, stream>>>(data, clusts, maskb, W1, y1);
  k_edge<<<E, 512, 0, stream>>>(eidx, y1, b1, W2, b2, W3, b3, Wfc, bfc,
                                (float*)d_out, E);
}

// Round 13
// 1058.458 us; speedup vs baseline: 1.8958x; 1.7047x over previous
//
#include <hip/hip_runtime.h>

// Problem constants: N=32768 pts, C=256 clusters, P=128, E=1024 edges,
// grid 32^3. Channels 1->16->32->64, three stride-2 SAME convs.
#define PPC 128

// Fractional box-overlap of [v, v+gs] with cell [i/32, (i+1)/32], divided by gs.
__device__ __forceinline__ float ovlap(float v, float gs, float inv_gs, int i) {
  const float ns = 0.03125f;                 // 1/32, exact
  float lo = (float)i * ns;                  // exact (multiple of 2^-5)
  float o  = fminf(v + gs, lo + ns) - fmaxf(v, lo);
  return fmaxf(o, 0.0f) * inv_gs;
}

// ---------------------------------------------------------------------------
// Kernel 1: per-cluster voxelize (in LDS) + conv1 (preact, no bias/relu)
//   y1[c][oc(16)][z16][y16][x16]  (fp32, 64 MB in d_ws)   (unchanged)
// ---------------------------------------------------------------------------
__global__ __launch_bounds__(256) void k_vox_conv1(
    const float* __restrict__ data,           // [32768,5]
    const int*   __restrict__ clusts,         // [C,128]
    const unsigned char* __restrict__ maskb,  // [C,128] bool bytes (or int32 - detected)
    const float* __restrict__ W1,             // [16,27]
    float* __restrict__ y1)                   // [C,16,4096]
{
  __shared__ float vox[32768];
  __shared__ float rmn[PPC * 3];
  __shared__ float rmx[PPC * 3];
  const int c = blockIdx.x;
  const int t = threadIdx.x;

  for (int i = t; i < 32768; i += 256) vox[i] = 0.f;

  const bool m32 = (maskb[1] == 0);   // mask dtype sniff (all-true mask)

  if (t < PPC) {
    int idx = clusts[c * PPC + t];
    const float* dp = data + idx * 5;
    bool m = m32 ? (((const int*)maskb)[c * PPC + t] != 0)
                 : (maskb[c * PPC + t] != 0);
#pragma unroll
    for (int d = 0; d < 3; ++d) {
      float p = dp[d];
      rmn[t * 3 + d] = m ? p : 1e9f;
      rmx[t * 3 + d] = m ? p : -1e9f;
    }
  }
  __syncthreads();
  for (int off = 64; off >= 1; off >>= 1) {
    if (t < off) {
#pragma unroll
      for (int d = 0; d < 3; ++d) {
        rmn[t * 3 + d] = fminf(rmn[t * 3 + d], rmn[(t + off) * 3 + d]);
        rmx[t * 3 + d] = fmaxf(rmx[t * 3 + d], rmx[(t + off) * 3 + d]);
      }
    }
    __syncthreads();
  }
  const float mn0 = rmn[0], mn1 = rmn[1], mn2 = rmn[2];
  const float rg0 = rmx[0] - mn0, rg1 = rmx[1] - mn1, rg2 = rmx[2] - mn2;
  const float mr = fmaxf(rg0, fmaxf(rg1, rg2)) + 1.0f;
  const float gs = 1.0f / mr;
  const float inv_gs = 1.0f / gs;

  {  // scatter: 2 threads per point, split outer-i by parity
    const int p = t >> 1, h = t & 1;
    int idx = clusts[c * PPC + p];
    const float* dp = data + idx * 5;
    bool m = m32 ? (((const int*)maskb)[c * PPC + p] != 0)
                 : (maskb[c * PPC + p] != 0);
    float w = m ? dp[4] : 0.f;
    if (w != 0.f) {
      float v0 = (dp[0] - mn0 - rg0 * 0.5f - 0.5f) * gs + 0.5f;
      float v1 = (dp[1] - mn1 - rg1 * 0.5f - 0.5f) * gs + 0.5f;
      float v2 = (dp[2] - mn2 - rg2 * 0.5f - 0.5f) * gs + 0.5f;
      int i0 = max(0, (int)floorf(v0 * 32.f) - 1), i1 = min(31, (int)floorf((v0 + gs) * 32.f) + 1);
      int j0 = max(0, (int)floorf(v1 * 32.f) - 1), j1 = min(31, (int)floorf((v1 + gs) * 32.f) + 1);
      int k0 = max(0, (int)floorf(v2 * 32.f) - 1), k1 = min(31, (int)floorf((v2 + gs) * 32.f) + 1);
      for (int i = i0 + h; i <= i1; i += 2) {
        float oi = ovlap(v0, gs, inv_gs, i);
        if (oi <= 0.f) continue;
        float wi = w * oi;
        for (int j = j0; j <= j1; ++j) {
          float oj = ovlap(v1, gs, inv_gs, j);
          if (oj <= 0.f) continue;
          float wij = wi * oj;
          for (int k = k0; k <= k1; ++k) {
            float ok = ovlap(v2, gs, inv_gs, k);
            if (ok > 0.f) atomicAdd(&vox[(i << 10) + (j << 5) + k], wij * ok);
          }
        }
      }
    }
  }
  __syncthreads();

  // conv1: 16 spatials/thread, 16 oc each. SAME: in = 2o+t, right-pad at 32.
  for (int si = 0; si < 16; ++si) {
    int s = t + (si << 8);
    int oz = s >> 8, oy = (s >> 4) & 15, ox = s & 15;
    float xv[27];
#pragma unroll
    for (int td = 0; td < 3; ++td)
#pragma unroll
      for (int th = 0; th < 3; ++th)
#pragma unroll
        for (int tw = 0; tw < 3; ++tw) {
          int z = 2 * oz + td, y = 2 * oy + th, x = 2 * ox + tw;
          bool okb = (z < 32) & (y < 32) & (x < 32);
          xv[(td * 3 + th) * 3 + tw] = okb ? vox[(z << 10) + (y << 5) + x] : 0.f;
        }
#pragma unroll
    for (int oc = 0; oc < 16; ++oc) {
      float a = 0.f;
#pragma unroll
      for (int tp = 0; tp < 27; ++tp) a = fmaf(W1[oc * 27 + tp], xv[tp], a);
      y1[(((c << 4) + oc) << 12) + s] = a;
    }
  }
}

// ---------------------------------------------------------------------------
// Kernel 2 (R13 = R8 baseline + two validated substitutions):
//  R9/R11/R12 structural rewrites all regressed vs R8's 810us (VGPR blowups)
//  -> compute loops are EXACTLY R8's (xv[27] arrays, oc-inner-32, unroll 1).
//  SUB 1: staging body float4 + shift-only addressing (R12-validated map).
//    R8's staging had 3 magic-mul divide chains PER ELEMENT (~1000 VALU/round
//    vs 1728 FMA) -- that was the issued-stream fat. Now 16 dwordx4 + ~150 VALU.
//  SUB 2: conv3 zero-once (R10-validated) + explicit barrier after conv2 loop
//    (R8 raced conv3 zeroing vs last compute reads and won by luck).
//  Parity-deinterleaved x layout kept everywhere (writes: even x->cols 0..7,
//  odd x->cols 9..16; reads {ox0, 9+ox0, ox0+1}; col 8 = pad, zeroed once).
// ---------------------------------------------------------------------------
#define S1 4913                // 17*17*17 one-channel staging volume
__global__ __launch_bounds__(256) void k_edge(
    const void*  __restrict__ eidx_raw,       // [2,E] int32 or int64 (detected)
    const float* __restrict__ y1,             // [C,16,4096]
    const float* __restrict__ b1,             // 16
    const float* __restrict__ W2,             // [32,16,27]
    const float* __restrict__ b2,             // 32
    const float* __restrict__ W3,             // [64,32,27]
    const float* __restrict__ b3,             // 64
    const float* __restrict__ Wfc,            // [64,64] (k-major)
    const float* __restrict__ bfc,            // 64
    float* __restrict__ out,                  // [E,64]
    int E)
{
  __shared__ float smem[2 * S1 + 64];         // stage bufs / conv3 buf (aliased) + pooled
  float* pooled = smem + 2 * S1;
  const int e = blockIdx.x;
  const int t = threadIdx.x;

  // edge_index dtype sniff (values < 256 -> int64 high words are 0)
  const int* e32 = (const int*)eidx_raw;
  const long long* e64 = (const long long*)eidx_raw;
  const bool is64 = (e32[1] == 0) & (e32[3] == 0) & (e32[5] == 0) & (e32[7] == 0);
  const int ca = is64 ? (int)e64[e] : e32[e];
  const int cb = is64 ? (int)e64[E + e] : e32[E + e];
  const float* Ap = y1 + (size_t)ca * 65536;
  const float* Bp = y1 + (size_t)cb * 65536;

  float acc2[2][32];
#pragma unroll
  for (int h = 0; h < 2; ++h)
#pragma unroll
    for (int o = 0; o < 32; ++o) acc2[h][o] = 0.f;

  const int oz0 = t >> 6, oy0 = (t >> 3) & 7, ox0 = t & 7;  // conv2 spatial: s0=t, s1=t+256
  // float4 stage map: per channel, float4 idx = p*256+t ->
  //   z = idx>>6 = p*4 + (t>>6), y = (idx>>2)&15, xq = idx&3
  //   x = 4*xq + {0,1,2,3} -> parity cols (y*17 + 2xq) + {0,9,1,10}
  const int sty = ((t >> 2) & 15) * 17 + 2 * (t & 3);
  const int stz = t >> 6;

  // zero both stage buffers once (pad cells: col 8, y=16, z=16);
  // first loop-top barrier separates this from the first stage.
  for (int i = t; i < 2 * S1; i += 256) smem[i] = 0.f;

  // ================= conv2: 8 rounds x 2 channels (R8 shape) ===============
  for (int icg = 0; icg < 8; ++icg) {
    __syncthreads();
    // ---- SUB 1: float4 shift-only staging of channels 2icg, 2icg+1 ----
#pragma unroll
    for (int icl = 0; icl < 2; ++icl) {
      const int ic = icg * 2 + icl;
      const float4* A4 = (const float4*)(Ap + (ic << 12));
      const float4* B4 = (const float4*)(Bp + (ic << 12));
      const float bb = b1[ic];
      const int wb = icl * S1;
#pragma unroll 2
      for (int p = 0; p < 4; ++p) {
        float4 av = A4[p * 256 + t];
        float4 bv = B4[p * 256 + t];
        const int w = wb + ((p << 2) + stz) * 289 + sty;
        smem[w]      = fmaxf(av.x + bv.x + bb, 0.f);
        smem[w + 9]  = fmaxf(av.y + bv.y + bb, 0.f);
        smem[w + 1]  = fmaxf(av.z + bv.z + bb, 0.f);
        smem[w + 10] = fmaxf(av.w + bv.w + bb, 0.f);
      }
    }
    __syncthreads();
    // ---- compute: EXACTLY R8's form ----
#pragma unroll 1
    for (int icl = 0; icl < 2; ++icl) {
      const int ic = icg * 2 + icl;
      const int rb = icl * S1 + oz0 * 578 + oy0 * 34;   // zz=2oz0, yy=2oy0
      float xv0[27], xv1[27];
#pragma unroll
      for (int td = 0; td < 3; ++td)
#pragma unroll
        for (int th = 0; th < 3; ++th) {
          const int b0 = rb + td * 289 + th * 17;
          const int tpb = (td * 3 + th) * 3;
          xv0[tpb + 0] = smem[b0 + ox0];
          xv0[tpb + 1] = smem[b0 + 9 + ox0];
          xv0[tpb + 2] = smem[b0 + ox0 + 1];
          xv1[tpb + 0] = smem[b0 + 2312 + ox0];        // s1: +8 in z = +8*289
          xv1[tpb + 1] = smem[b0 + 2312 + 9 + ox0];
          xv1[tpb + 2] = smem[b0 + 2312 + ox0 + 1];
        }
      const float* wrow = W2 + ic * 27;        // + oc*432 (uniform -> s_load)
#pragma unroll
      for (int oc = 0; oc < 32; ++oc) {
#pragma unroll
        for (int tp = 0; tp < 27; ++tp) {
          const float w = wrow[oc * 432 + tp];
          acc2[0][oc] = fmaf(w, xv0[tp], acc2[0][oc]);
          acc2[1][oc] = fmaf(w, xv1[tp], acc2[1][oc]);
        }
      }
    }
  }
  __syncthreads();   // SUB 2a: fence last compute's reads before conv3 zeroing

  // ================= conv3: 4 oc-quarters, padded [8][9][9][9] =============
  // SUB 2b: zero ONCE (pads: z=8 plane, y=8 rows, col 4); interiors rewritten.
  for (int i = t; i < 5832; i += 256) smem[i] = 0.f;
  __syncthreads();

  float acc3[16];
#pragma unroll
  for (int o = 0; o < 16; ++o) acc3[o] = 0.f;
  const int l = t & 63, wid = t >> 6;
  const int OZ = l >> 4, OY = (l >> 2) & 3, OX = l & 3;     // conv3 spatial 4^3
  const int rb3 = OZ * 162 + OY * 18;                       // zz=2OZ, yy=2OY
  const int cox = (ox0 >> 1) + (ox0 & 1) * 5;               // x2-write column

#pragma unroll
  for (int q = 0; q < 4; ++q) {
#pragma unroll
    for (int h = 0; h < 2; ++h)
#pragma unroll
      for (int o = 0; o < 8; ++o) {
        const int oc = (q << 3) + o;           // compile-time (q,o unrolled)
        smem[o * 729 + (oz0 + (h << 2)) * 81 + oy0 * 9 + cox] =
            fmaxf(acc2[h][oc] + b2[oc], 0.f);
      }
    __syncthreads();
#pragma unroll 1
    for (int icl = 0; icl < 8; ++icl) {
      const int ic3 = (q << 3) + icl;
      float xv[27];
#pragma unroll
      for (int td = 0; td < 3; ++td)
#pragma unroll
        for (int th = 0; th < 3; ++th) {
          const int bb = icl * 729 + rb3 + td * 81 + th * 9;
          const int tpb = (td * 3 + th) * 3;
          xv[tpb + 0] = smem[bb + OX];          // x=2OX
          xv[tpb + 1] = smem[bb + 5 + OX];      // x=2OX+1
          xv[tpb + 2] = smem[bb + OX + 1];      // x=2OX+2 (OX=3 -> col4 pad = 0)
        }
#pragma unroll
      for (int o = 0; o < 16; ++o) {
        const int oc = (wid << 4) + o;
        const float* wr = W3 + (oc * 32 + ic3) * 27;   // uniform -> s_load
#pragma unroll
        for (int tp = 0; tp < 27; ++tp) acc3[o] = fmaf(wr[tp], xv[tp], acc3[o]);
      }
    }
    __syncthreads();
  }

  // ================= bias+relu, mean-pool over 64 spatials, FC =============
#pragma unroll
  for (int o = 0; o < 16; ++o) {
    float r = fmaxf(acc3[o] + b3[(wid << 4) + o], 0.f);
    r += __shfl_xor(r, 1);
    r += __shfl_xor(r, 2);
    r += __shfl_xor(r, 4);
    r += __shfl_xor(r, 8);
    r += __shfl_xor(r, 16);
    r += __shfl_xor(r, 32);
    if (l == 0) pooled[(wid << 4) + o] = r * 0.015625f;  // /64
  }
  __syncthreads();
  if (t < 64) {
    float a = bfc[t];
#pragma unroll 8
    for (int k = 0; k < 64; ++k) a = fmaf(pooled[k], Wfc[(k << 6) + t], a);
    out[e * 64 + t] = a;
  }
}

// ---------------------------------------------------------------------------
extern "C" void kernel_launch(void* const* d_in, const int* in_sizes, int n_in,
                              void* d_out, int out_size, void* d_ws, size_t ws_size,
                              hipStream_t stream) {
  const float* data = (const float*)d_in[0];
  const int*   clusts = (const int*)d_in[1];
  const unsigned char* maskb = (const unsigned char*)d_in[2];
  const void*  eidx = d_in[3];
  const float* W1 = (const float*)d_in[4];
  const float* b1 = (const float*)d_in[5];
  const float* W2 = (const float*)d_in[6];
  const float* b2 = (const float*)d_in[7];
  const float* W3 = (const float*)d_in[8];
  const float* b3 = (const float*)d_in[9];
  const float* Wfc = (const float*)d_in[10];
  const float* bfc = (const float*)d_in[11];

  const int C = in_sizes[1] / PPC;   // 256
  const int E = in_sizes[3] / 2;     // 1024

  float* y1 = (float*)d_ws;          // C*16*4096 floats = 64 MB

  k_vox_conv1<<<C, 256, 0, stream>>>(data, clusts, maskb, W1, y1);
  k_edge<<<E, 256, 0, stream>>>(eidx, y1, b1, W2, b2, W3, b3, Wfc, bfc,
                                (float*)d_out, E);
}